// Round 1
// baseline (981.610 us; speedup 1.0000x reference)
//
#include <hip/hip_runtime.h>
#include <hip/hip_bf16.h>

// LoRALinear: out = x @ (W + 2.0*B@A)^T + bias
// M=16384, N=4096, K=4096, R=16.
// Plan: (1) cast x fp32->bf16 into ws, (2) W_eff = W + 2*B@A -> bf16 into ws,
// (3) bf16 MFMA GEMM (m97 structure: 128^2 tile, BK=32, global_load_lds w=16,
//     XCD-swizzled blockIdx) with fused bias epilogue, fp32 out.
// ws layout: [0,134217728) x_bf16 ; [134217728, +33554432) W_eff_bf16.

typedef __attribute__((ext_vector_type(8))) short bf16x8;
typedef __attribute__((ext_vector_type(4))) float f32x4;
typedef __attribute__((ext_vector_type(4))) unsigned short u16x4;

#define M_DIM 16384
#define N_DIM 4096
#define K_DIM 4096
#define TILE 128
#define BK 32

__device__ __forceinline__ unsigned short f2bf(float f) {
    // RNE float->bf16 (finite data only)
    unsigned int u = __builtin_bit_cast(unsigned int, f);
    unsigned int r = u + 0x7FFFu + ((u >> 16) & 1u);
    return (unsigned short)(r >> 16);
}

__device__ __forceinline__ void async16(const void* g, void* l) {
    __builtin_amdgcn_global_load_lds(
        (const __attribute__((address_space(1))) unsigned int*)g,
        (__attribute__((address_space(3))) unsigned int*)l,
        16, 0, 0);
}

// ---------------- prep kernel 1: x fp32 -> bf16 ----------------
__global__ void __launch_bounds__(256) cast_x_kernel(
    const float4* __restrict__ x, u16x4* __restrict__ y, int n4) {
    int i = blockIdx.x * blockDim.x + threadIdx.x;
    int stride = gridDim.x * blockDim.x;
    for (; i < n4; i += stride) {
        float4 v = x[i];
        u16x4 o = { f2bf(v.x), f2bf(v.y), f2bf(v.z), f2bf(v.w) };
        y[i] = o;
    }
}

// ---------------- prep kernel 2: W_eff = W + 2*B@A -> bf16 ----------------
__global__ void __launch_bounds__(256) weff_kernel(
    const float* __restrict__ W, const float* __restrict__ lA,
    const float* __restrict__ lB, unsigned short* __restrict__ out) {
    constexpr int K = K_DIM, R = 16;
    constexpr float S = 2.0f;  // 32.0 / 16
    int o = blockIdx.x;
    int t = threadIdx.x;
    float b[R];
#pragma unroll
    for (int r = 0; r < R; ++r) b[r] = lB[o * R + r];
#pragma unroll
    for (int c = 0; c < 4; ++c) {
        int i = c * 1024 + t * 4;
        float4 wv = *reinterpret_cast<const float4*>(&W[o * K + i]);
        float sx = 0.f, sy = 0.f, sz = 0.f, sw = 0.f;
#pragma unroll
        for (int r = 0; r < R; ++r) {
            float4 a = *reinterpret_cast<const float4*>(&lA[r * K + i]);
            sx += b[r] * a.x; sy += b[r] * a.y;
            sz += b[r] * a.z; sw += b[r] * a.w;
        }
        u16x4 ov = { f2bf(wv.x + S * sx), f2bf(wv.y + S * sy),
                     f2bf(wv.z + S * sz), f2bf(wv.w + S * sw) };
        *reinterpret_cast<u16x4*>(&out[o * K + i]) = ov;
    }
}

// ---------------- main GEMM: C[m][n] = sum_k A[m][k]*B[n][k] + bias[n] ----------------
// A: x_bf16 [M][K] row-major; B: W_eff [N][K] row-major (i.e. B^T input, K contiguous).
// 256 threads = 4 waves in 2x2; each wave owns a 64x64 output sub-tile:
// acc[4][4] fragments of 16x16, MFMA 16x16x32 bf16.
__global__ void __launch_bounds__(256) gemm_bias_kernel(
    const unsigned short* __restrict__ A,
    const unsigned short* __restrict__ B,
    const float* __restrict__ bias,
    float* __restrict__ C) {
    constexpr int K = K_DIM, N = N_DIM;
    __shared__ unsigned short sA[TILE * BK];  // 8 KiB
    __shared__ unsigned short sB[TILE * BK];  // 8 KiB

    const int t = threadIdx.x;
    const int l = t & 63;
    const int w = t >> 6;
    const int wm = w >> 1, wn = w & 1;

    // XCD-aware bijective swizzle (nwg = 4096, divisible by 8)
    const int nwg = gridDim.x;
    const int cpx = nwg >> 3;
    const int bid = blockIdx.x;
    const int swz = (bid & 7) * cpx + (bid >> 3);
    const int bm = swz >> 5;   // / (N/TILE) = 32
    const int bn = swz & 31;

    const unsigned short* gA = A + bm * TILE * K;
    const unsigned short* gB = B + bn * TILE * K;

    f32x4 acc[4][4] = {};

    const int lg = l >> 4;   // lane group 0..3 (K sub-slice)
    const int lr = l & 15;   // row within 16
    const int aoff = (wm * 64 + lr) * BK + lg * 8;
    const int boff = (wn * 64 + lr) * BK + lg * 8;

    // staging decomposition: thread t covers tile elements [8t, 8t+8)
    const int sr = t >> 2;            // row 0..63 (instr 0), +64 for instr 1
    const int sc = (t & 3) * 8;       // col 0,8,16,24
    const int wbase = (t & 192) * 8;  // wave-uniform LDS base (elements)

    for (int k0 = 0; k0 < K; k0 += BK) {
        async16(gA + sr * K + k0 + sc,        sA + wbase);
        async16(gA + (sr + 64) * K + k0 + sc, sA + 2048 + wbase);
        async16(gB + sr * K + k0 + sc,        sB + wbase);
        async16(gB + (sr + 64) * K + k0 + sc, sB + 2048 + wbase);
        __syncthreads();   // compiler emits s_waitcnt vmcnt(0) before barrier

        bf16x8 af[4], bf[4];
#pragma unroll
        for (int i = 0; i < 4; ++i)
            af[i] = *reinterpret_cast<const bf16x8*>(&sA[aoff + i * 16 * BK]);
#pragma unroll
        for (int i = 0; i < 4; ++i)
            bf[i] = *reinterpret_cast<const bf16x8*>(&sB[boff + i * 16 * BK]);

#pragma unroll
        for (int i = 0; i < 4; ++i)
#pragma unroll
            for (int j = 0; j < 4; ++j)
                acc[i][j] = __builtin_amdgcn_mfma_f32_16x16x32_bf16(
                    af[i], bf[j], acc[i][j], 0, 0, 0);

        __syncthreads();
    }

    // epilogue: D row = (l>>4)*4 + r, col = l&15 (verified m89/m91 layout)
    const int row0 = bm * TILE + wm * 64;
    const int col0 = bn * TILE + wn * 64;
#pragma unroll
    for (int j = 0; j < 4; ++j) {
        const int col = col0 + j * 16 + lr;
        const float bv = bias[col];
#pragma unroll
        for (int i = 0; i < 4; ++i) {
            const int rbase = row0 + i * 16 + lg * 4;
#pragma unroll
            for (int r = 0; r < 4; ++r)
                C[(rbase + r) * N + col] = acc[i][j][r] + bv;
        }
    }
}

extern "C" void kernel_launch(void* const* d_in, const int* in_sizes, int n_in,
                              void* d_out, int out_size, void* d_ws, size_t ws_size,
                              hipStream_t stream) {
    const float* x    = (const float*)d_in[0];  // [4,4096,4096]
    const float* W    = (const float*)d_in[1];  // [4096,4096]
    const float* bias = (const float*)d_in[2];  // [4096]
    const float* lA   = (const float*)d_in[3];  // [16,4096]
    const float* lB   = (const float*)d_in[4];  // [4096,16]
    float* out = (float*)d_out;

    unsigned short* xb   = (unsigned short*)d_ws;                       // 134217728 B
    unsigned short* weff = (unsigned short*)((char*)d_ws + 134217728);  // 33554432 B

    cast_x_kernel<<<2048, 256, 0, stream>>>((const float4*)x, (u16x4*)xb,
                                            M_DIM * K_DIM / 4);
    weff_kernel<<<N_DIM, 256, 0, stream>>>(W, lA, lB, weff);
    gemm_bias_kernel<<<(M_DIM / TILE) * (N_DIM / TILE), 256, 0, stream>>>(
        xb, weff, bias, out);
}

// Round 2
// 604.379 us; speedup vs baseline: 1.6242x; 1.6242x over previous
//
#include <hip/hip_runtime.h>
#include <hip/hip_bf16.h>

// LoRALinear: out = x @ (W + 2.0*B@A)^T + bias ; M=16384, N=4096, K=4096, R=16.
// Round 2: 256x256-tile 8-phase GEMM (m201 template: T2 LDS XOR-swizzle +
// T3/T4 phased counted-vmcnt pipeline + T5 setprio). Preps unchanged.
// ws layout: [0,134217728) x_bf16 ; [134217728, +33554432) W_eff_bf16.

typedef __attribute__((ext_vector_type(8))) short bf16x8;
typedef __attribute__((ext_vector_type(4))) float f32x4;
typedef __attribute__((ext_vector_type(4))) unsigned short u16x4;

#define M_DIM 16384
#define N_DIM 4096
#define K_DIM 4096
#define NT (K_DIM / 64)   // 64 K-tiles of BK=64

__device__ __forceinline__ unsigned short f2bf(float f) {
    unsigned int u = __builtin_bit_cast(unsigned int, f);
    unsigned int r = u + 0x7FFFu + ((u >> 16) & 1u);
    return (unsigned short)(r >> 16);
}

__device__ __forceinline__ void async16(const void* g, void* l) {
    __builtin_amdgcn_global_load_lds(
        (const __attribute__((address_space(1))) unsigned int*)g,
        (__attribute__((address_space(3))) unsigned int*)l,
        16, 0, 0);
}

// ---------------- prep kernel 1: x fp32 -> bf16 ----------------
__global__ void __launch_bounds__(256) cast_x_kernel(
    const float4* __restrict__ x, u16x4* __restrict__ y, int n4) {
    int i = blockIdx.x * blockDim.x + threadIdx.x;
    int stride = gridDim.x * blockDim.x;
    for (; i < n4; i += stride) {
        float4 v = x[i];
        u16x4 o = { f2bf(v.x), f2bf(v.y), f2bf(v.z), f2bf(v.w) };
        y[i] = o;
    }
}

// ---------------- prep kernel 2: W_eff = W + 2*B@A -> bf16 ----------------
__global__ void __launch_bounds__(256) weff_kernel(
    const float* __restrict__ W, const float* __restrict__ lA,
    const float* __restrict__ lB, unsigned short* __restrict__ out) {
    constexpr int K = K_DIM, R = 16;
    constexpr float S = 2.0f;  // 32.0 / 16
    int o = blockIdx.x;
    int t = threadIdx.x;
    float b[R];
#pragma unroll
    for (int r = 0; r < R; ++r) b[r] = lB[o * R + r];
#pragma unroll
    for (int c = 0; c < 4; ++c) {
        int i = c * 1024 + t * 4;
        float4 wv = *reinterpret_cast<const float4*>(&W[o * K + i]);
        float sx = 0.f, sy = 0.f, sz = 0.f, sw = 0.f;
#pragma unroll
        for (int r = 0; r < R; ++r) {
            float4 a = *reinterpret_cast<const float4*>(&lA[r * K + i]);
            sx += b[r] * a.x; sy += b[r] * a.y;
            sz += b[r] * a.z; sw += b[r] * a.w;
        }
        u16x4 ov = { f2bf(wv.x + S * sx), f2bf(wv.y + S * sy),
                     f2bf(wv.z + S * sz), f2bf(wv.w + S * sw) };
        *reinterpret_cast<u16x4*>(&out[o * K + i]) = ov;
    }
}

// ---------------- main GEMM: 256x256 tile, 8-wave, 8-phase ----------------
// A: x_bf16 [M][K]; B: W_eff [N][K]. C[m][n] = sum_k A[m][k]B[n][k] + bias[n].
// LDS buffer (x2): A tile 256x64 bf16 [0,32768) + B tile 256x64 [32768,65536),
// 128B rows, XOR-swizzled: phys = row*128 + ((colbyte) ^ ((row&7)<<4)).
// Stage is linear (global_load_lds); the global source is lane-pre-swizzled
// (lane lam = l ^ (l>>3)) so swizzled reads find their data (rule #21).
#define STAGE(G, h, tt, bsel, moff)                                           \
    do {                                                                      \
        const unsigned short* g0 = (G) +                                      \
            (size_t)((h) * 128 + wid * 16 + rc) * K_DIM + (tt) * 64 + cc * 8; \
        char* l0 = lds + (bsel) * 65536 + (moff) + (h) * 16384 + wid * 2048;  \
        async16(g0, l0);                                                      \
        async16(g0 + 8 * K_DIM, l0 + 1024);                                   \
    } while (0)

#define LDA(mh, bsel)                                                         \
    _Pragma("unroll") for (int mm = 0; mm < 4; ++mm)                          \
    _Pragma("unroll") for (int ks = 0; ks < 2; ++ks)                          \
        ar[mm][ks] = *(const bf16x8*)(lds + (bsel) * 65536 +                  \
            ((aBase + ((mh) * 4 + mm) * 2048) ^ (ks << 6)));

#define LDB(nh, bsel)                                                         \
    _Pragma("unroll") for (int nn = 0; nn < 2; ++nn)                          \
    _Pragma("unroll") for (int ks = 0; ks < 2; ++ks)                          \
        br[(nh) * 2 + nn][ks] = *(const bf16x8*)(lds + (bsel) * 65536 +       \
            ((bBase + ((nh) * 2 + nn) * 2048) ^ (ks << 6)));

#define MM(mh, nh)                                                            \
    _Pragma("unroll") for (int ks = 0; ks < 2; ++ks)                          \
    _Pragma("unroll") for (int mm = 0; mm < 4; ++mm)                          \
    _Pragma("unroll") for (int nn = 0; nn < 2; ++nn)                          \
        acc[(mh) * 4 + mm][(nh) * 2 + nn] =                                   \
            __builtin_amdgcn_mfma_f32_16x16x32_bf16(                          \
                ar[mm][ks], br[(nh) * 2 + nn][ks],                            \
                acc[(mh) * 4 + mm][(nh) * 2 + nn], 0, 0, 0);

#define PHASE_MID()                                                           \
    __builtin_amdgcn_s_barrier();                                             \
    asm volatile("s_waitcnt lgkmcnt(0)" ::: "memory");                        \
    __builtin_amdgcn_s_setprio(1)

#define PHASE_END()                                                           \
    __builtin_amdgcn_s_setprio(0);                                            \
    __builtin_amdgcn_s_barrier()

__global__ void __launch_bounds__(512, 2) gemm8p_kernel(
    const unsigned short* __restrict__ A,
    const unsigned short* __restrict__ B,
    const float* __restrict__ bias,
    float* __restrict__ C) {
    __shared__ __align__(1024) char lds[131072];

    const int tid = threadIdx.x;
    const int lane = tid & 63, wid = tid >> 6;
    const int wm = wid >> 2, wn = wid & 3;   // 2 x 4 waves
    const int lr = lane & 15, lg = lane >> 4;

    // XCD-aware swizzle: 1024 blocks (divisible by 8)
    const int bid = blockIdx.x;
    const int swz = (bid & 7) * 128 + (bid >> 3);
    const int bm = swz >> 4, bn = swz & 15;  // 64 x 16 tiles

    const unsigned short* Ag = A + (size_t)bm * 256 * K_DIM;
    const unsigned short* Bg = B + (size_t)bn * 256 * K_DIM;

    // staging lane pre-swizzle (inverse of the read XOR)
    const int lam = lane ^ (lane >> 3);
    const int rc = lam >> 3, cc = lam & 7;

    // read-side swizzled bases
    const int kx0 = (lg * 16) ^ ((lr & 7) << 4);
    const int aBase = (wm * 128 + lr) * 128 + kx0;           // A region
    const int bBase = 32768 + (wn * 64 + lr) * 128 + kx0;    // B region

    f32x4 acc[8][4] = {};
    bf16x8 ar[4][2], br[4][2];

    // prologue: t0.B0, t0.B1, t0.A0, t0.A1, t1.B0, t1.B1
    STAGE(Bg, 0, 0, 0, 32768);
    STAGE(Bg, 1, 0, 0, 32768);
    STAGE(Ag, 0, 0, 0, 0);
    STAGE(Ag, 1, 0, 0, 0);
    STAGE(Bg, 0, 1, 1, 32768);
    STAGE(Bg, 1, 1, 1, 32768);
    asm volatile("s_waitcnt vmcnt(4)" ::: "memory");
    __builtin_amdgcn_s_barrier();

#pragma unroll 2
    for (int t = 0; t < NT; ++t) {
        const int bs = t & 1, bo = bs ^ 1;
        // ---- phase 0: quadrant (mh=0, nh=0)
        LDA(0, bs);
        LDB(0, bs);
        if (t + 1 < NT) STAGE(Ag, 0, t + 1, bo, 0);
        PHASE_MID();
        MM(0, 0);
        PHASE_END();
        // ---- phase 1: (0,1)
        LDB(1, bs);
        if (t + 1 < NT) STAGE(Ag, 1, t + 1, bo, 0);
        PHASE_MID();
        MM(0, 1);
        PHASE_END();
        // ---- phase 2: (1,0)
        LDA(1, bs);
        if (t + 2 < NT) STAGE(Bg, 0, t + 2, bs, 32768);
        PHASE_MID();
        MM(1, 0);
        PHASE_END();
        // ---- phase 3: (1,1) + K-tile boundary counted vmcnt
        if (t + 2 < NT) STAGE(Bg, 1, t + 2, bs, 32768);
        PHASE_MID();
        MM(1, 1);
        __builtin_amdgcn_s_setprio(0);
        if (t + 2 < NT) {
            asm volatile("s_waitcnt vmcnt(4)" ::: "memory");
        } else {
            asm volatile("s_waitcnt vmcnt(0)" ::: "memory");
        }
        __builtin_amdgcn_s_barrier();
    }

    // epilogue: D col=lane&15, row=(lane>>4)*4+r (verified m89/m91)
    const int row0 = bm * 256 + wm * 128;
    const int col0 = bn * 256 + wn * 64;
#pragma unroll
    for (int n = 0; n < 4; ++n) {
        const int col = col0 + n * 16 + lr;
        const float bv = bias[col];
#pragma unroll
        for (int m = 0; m < 8; ++m) {
            const int r0 = row0 + m * 16 + lg * 4;
#pragma unroll
            for (int r = 0; r < 4; ++r)
                C[(size_t)(r0 + r) * N_DIM + col] = acc[m][n][r] + bv;
        }
    }
}

extern "C" void kernel_launch(void* const* d_in, const int* in_sizes, int n_in,
                              void* d_out, int out_size, void* d_ws, size_t ws_size,
                              hipStream_t stream) {
    const float* x    = (const float*)d_in[0];  // [4,4096,4096]
    const float* W    = (const float*)d_in[1];  // [4096,4096]
    const float* bias = (const float*)d_in[2];  // [4096]
    const float* lA   = (const float*)d_in[3];  // [16,4096]
    const float* lB   = (const float*)d_in[4];  // [4096,16]
    float* out = (float*)d_out;

    unsigned short* xb   = (unsigned short*)d_ws;                       // 134 MB
    unsigned short* weff = (unsigned short*)((char*)d_ws + 134217728);  // 32 MB

    cast_x_kernel<<<2048, 256, 0, stream>>>((const float4*)x, (u16x4*)xb,
                                            M_DIM * K_DIM / 4);
    weff_kernel<<<N_DIM, 256, 0, stream>>>(W, lA, lB, weff);
    gemm8p_kernel<<<(M_DIM / 256) * (N_DIM / 256), 512, 0, stream>>>(
        xb, weff, bias, out);
}